// Round 4
// baseline (355.929 us; speedup 1.0000x reference)
//
#include <hip/hip_runtime.h>
#include <hip/hip_bf16.h>

typedef __bf16 bf16x8 __attribute__((ext_vector_type(8)));
typedef float f32x4 __attribute__((ext_vector_type(4)));
typedef float f32x16 __attribute__((ext_vector_type(16)));
typedef unsigned int uint2v __attribute__((ext_vector_type(2)));

#define EPSBN 1e-3f

constexpr int NPIX = 4096;   // H*W
constexpr int D2 = 256;      // C/2

// ---------- x -> bf16 ----------
__global__ __launch_bounds__(256) void k_cvt(const float* __restrict__ x,
                                             __bf16* __restrict__ xb, int n4) {
  int i = blockIdx.x * 256 + threadIdx.x;
  if (i >= n4) return;
  float4 v = reinterpret_cast<const float4*>(x)[i];
  union { __bf16 h[4]; uint2 u; } o;
  o.h[0] = (__bf16)v.x; o.h[1] = (__bf16)v.y; o.h[2] = (__bf16)v.z; o.h[3] = (__bf16)v.w;
  reinterpret_cast<uint2*>(xb)[i] = o.u;
}

// ---------- weight precompute ----------
__global__ __launch_bounds__(256) void kp_wfgh(const float* __restrict__ wf,
                                               const float* __restrict__ wg,
                                               const float* __restrict__ wh,
                                               __bf16* __restrict__ WT) {
  int idx = blockIdx.x * 256 + threadIdx.x;  // < 384*512
  int c = idx >> 9, k = idx & 511;
  float v = (c < 64) ? wf[k * 64 + c] : (c < 128) ? wg[k * 64 + (c - 64)] : wh[k * 256 + (c - 128)];
  WT[idx] = (__bf16)v;
}

__global__ __launch_bounds__(128) void kp_bias384(const float* bf_, const float* bg_,
                                                  const float* bh_, float* bias) {
  int c = blockIdx.x * 128 + threadIdx.x;  // grid 3 -> 384
  bias[c] = (c < 64) ? bf_[c] : (c < 128) ? bg_[c - 64] : bh_[c - 128];
}

__global__ __launch_bounds__(256) void kp_wow(const float* __restrict__ wo,
                                              const float* __restrict__ wc,
                                              float* __restrict__ Wow) {
  int idx = blockIdx.x * 256 + threadIdx.x;  // 256*512
  int d = idx >> 9, c = idx & 511;
  float acc = 0.f;
  for (int j = 0; j < 512; ++j) acc += wo[d * 512 + j] * wc[j * 512 + c];
  Wow[idx] = acc;
}

__global__ __launch_bounds__(256) void kp_wcat(const float* __restrict__ Wow,
                                               const float* __restrict__ wc,
                                               const float* __restrict__ gamma,
                                               const float* __restrict__ bns,
                                               const float* __restrict__ bnv,
                                               __bf16* __restrict__ WT) {
  int idx = blockIdx.x * 256 + threadIdx.x;  // 512*768
  int c = idx / 768, k = idx % 768;
  float s = bns[c] * rsqrtf(bnv[c] + EPSBN);
  float v;
  if (k < 256) v = gamma[0] * Wow[k * 512 + c] * s;
  else { int kk = k - 256; v = (wc[kk * 512 + c] + wc[(512 + kk) * 512 + c]) * s; }
  WT[idx] = (__bf16)v;
}

__global__ __launch_bounds__(256) void kp_biasF(const float* bo, const float* wc, const float* bc,
                                                const float* gamma, const float* bns, const float* bnb,
                                                const float* bnm, const float* bnv, float* biasF) {
  int c = blockIdx.x * 256 + threadIdx.x;  // grid 2 -> 512
  float s = bns[c] * rsqrtf(bnv[c] + EPSBN);
  float acc = 0.f;
  for (int j = 0; j < 512; ++j) acc += bo[j] * wc[j * 512 + c];
  float pre = bc[c] + gamma[0] * acc;
  biasF[c] = (pre - bnm[c]) * s + bnb[c];
}

// ---------- generic MFMA GEMM: C[M][NC] = A[M][KT] @ WT^T + bias ----------
template <int KT, int NC, int MODE>
__global__ __launch_bounds__(256) void k_gemm(const __bf16* __restrict__ A1, int k1, int lda1,
                                              const __bf16* __restrict__ A2, int lda2,
                                              const __bf16* __restrict__ WT,
                                              const float* __restrict__ bias,
                                              void* __restrict__ out1,
                                              void* __restrict__ out2) {
  __shared__ __bf16 As[128][72];
  __shared__ __bf16 Ws[64][72];
  const int m0 = blockIdx.x * 128, n0 = blockIdx.y * 64;
  const int tid = threadIdx.x, lane = tid & 63, w = tid >> 6;
  const int wr = w >> 1, wcl = w & 1;
  const int l15 = lane & 15, l4 = lane >> 4;
  f32x4 acc[4][2] = {};
  for (int ks = 0; ks < KT; ks += 64) {
    const __bf16* Asrc; int lda, kb;
    if (ks < k1) { Asrc = A1; lda = lda1; kb = ks; }
    else         { Asrc = A2; lda = lda2; kb = ks - k1; }
#pragma unroll
    for (int it = 0; it < 4; ++it) {
      int idx = it * 256 + tid, r = idx >> 3, ch = idx & 7;
      *(bf16x8*)(&As[r][ch * 8]) = *(const bf16x8*)(Asrc + (size_t)(m0 + r) * lda + kb + ch * 8);
    }
#pragma unroll
    for (int it = 0; it < 2; ++it) {
      int idx = it * 256 + tid, r = idx >> 3, ch = idx & 7;
      *(bf16x8*)(&Ws[r][ch * 8]) = *(const bf16x8*)(WT + (size_t)(n0 + r) * KT + ks + ch * 8);
    }
    __syncthreads();
#pragma unroll
    for (int kk = 0; kk < 2; ++kk) {
      int krd = kk * 32 + l4 * 8;
      bf16x8 av[4], bv[2];
#pragma unroll
      for (int mi = 0; mi < 4; ++mi) av[mi] = *(const bf16x8*)(&As[wr * 64 + mi * 16 + l15][krd]);
#pragma unroll
      for (int ni = 0; ni < 2; ++ni) bv[ni] = *(const bf16x8*)(&Ws[wcl * 32 + ni * 16 + l15][krd]);
#pragma unroll
      for (int mi = 0; mi < 4; ++mi)
#pragma unroll
        for (int ni = 0; ni < 2; ++ni)
          acc[mi][ni] = __builtin_amdgcn_mfma_f32_16x16x32_bf16(av[mi], bv[ni], acc[mi][ni], 0, 0, 0);
    }
    __syncthreads();
  }
#pragma unroll
  for (int mi = 0; mi < 4; ++mi)
#pragma unroll
    for (int ni = 0; ni < 2; ++ni) {
      int col = n0 + wcl * 32 + ni * 16 + l15;
      float bcol = bias[col];
      int row0 = m0 + wr * 64 + mi * 16 + l4 * 4;
      if (MODE == 1) {
        float* out = (float*)out1;
#pragma unroll
        for (int r = 0; r < 4; ++r)
          out[(size_t)(row0 + r) * NC + col] = fmaxf(acc[mi][ni][r] + bcol, 0.f);
      } else {
        if (col < 128) {
          __bf16* fg = (__bf16*)out1;
#pragma unroll
          for (int r = 0; r < 4; ++r)
            fg[(size_t)(row0 + r) * 128 + col] = (__bf16)(acc[mi][ni][r] + bcol);
        } else {
          __bf16* hvT = (__bf16*)out2;
          int bb = row0 >> 12, n = row0 & 4095;
          union { __bf16 h[4]; uint2 u; } pk;
#pragma unroll
          for (int r = 0; r < 4; ++r) pk.h[r] = (__bf16)(acc[mi][ni][r] + bcol);
          *(uint2*)(hvT + ((size_t)(bb * 256 + (col - 128))) * 4096 + n) = pk.u;
        }
      }
    }
}

// ---------- attention (in-register, barrier-free, m-split 2) ----------
// fg: [B*4096][128] (f cols 0..63, g cols 64..127), hvT: [B][256][4096]
// Each wave: 32 q-rows, full d=256, m-range 2048 (its split half).
// S^T via swapped mfma 32x32x16; P->A-fragment via cvt_pk_bf16 + permlane32_swap (T12).
// Partial O (bf16) and partial L (f32) written; k_comb combines.

__device__ __forceinline__ void plswap(unsigned int a, unsigned int b,
                                       unsigned int& x, unsigned int& y) {
#if __has_builtin(__builtin_amdgcn_permlane32_swap)
  uint2v r = __builtin_amdgcn_permlane32_swap(a, b, false, false);
  x = r.x; y = r.y;
#else
  unsigned int as = __shfl_xor((int)a, 32), bs = __shfl_xor((int)b, 32);
  int hi = (threadIdx.x & 63) >> 5;
  x = hi ? bs : a;   // {a_lo | b_lo}
  y = hi ? b : as;   // {a_hi | b_hi}
#endif
}

__global__ __launch_bounds__(256, 1) void k_attn(const __bf16* __restrict__ fg,
                                                 const __bf16* __restrict__ hvT,
                                                 __bf16* __restrict__ PO,
                                                 float* __restrict__ Lbuf) {
  __shared__ __bf16 T[4][32][264];
  const int id = blockIdx.x;
  const int grp = id & 7;                 // XCD-pinned (b, ms) group
  const int b = grp >> 1, ms = grp & 1;
  const int qb = id >> 3;                 // 0..31
  const int tid = threadIdx.x, w = tid >> 6, lane = tid & 63;
  const int l31 = lane & 31, hi = lane >> 5;
  const int q0w = qb * 128 + w * 32;
  const int mbase = ms * 2048;
  const __bf16* fgb = fg + (size_t)b * NPIX * 128;
  const __bf16* vb = hvT + (size_t)b * D2 * NPIX;

  // G fragments (resident): B-operand, col=q=l31, k=c=kt*16+hi*8+j
  bf16x8 bG[4];
#pragma unroll
  for (int kt = 0; kt < 4; ++kt)
    bG[kt] = *(const bf16x8*)(fgb + (size_t)(q0w + l31) * 128 + 64 + kt * 16 + hi * 8);

  f32x16 accO[8] = {};
  float lsum = 0.f;

  bf16x8 aFA[4], aFB[4], bVA[8][2], bVB[8][2];
#pragma unroll
  for (int kt = 0; kt < 4; ++kt)
    aFA[kt] = *(const bf16x8*)(fgb + (size_t)(mbase + l31) * 128 + kt * 16 + hi * 8);
#pragma unroll
  for (int dt = 0; dt < 8; ++dt) {
    bVA[dt][0] = *(const bf16x8*)(vb + (size_t)(dt * 32 + l31) * NPIX + mbase + hi * 8);
    bVA[dt][1] = *(const bf16x8*)(vb + (size_t)(dt * 32 + l31) * NPIX + mbase + 16 + hi * 8);
  }

#define TILE_BODY(MB, MN, AF, AFN, BV, BVN) do {                                        \
    f32x16 s = {};                                                                      \
    _Pragma("unroll")                                                                   \
    for (int kt = 0; kt < 4; ++kt)                                                      \
      s = __builtin_amdgcn_mfma_f32_32x32x16_bf16(AF[kt], bG[kt], s, 0, 0, 0);          \
    _Pragma("unroll")                                                                   \
    for (int kt = 0; kt < 4; ++kt)                                                      \
      AFN[kt] = *(const bf16x8*)(fgb + (size_t)((MN) + l31) * 128 + kt * 16 + hi * 8);  \
    _Pragma("unroll")                                                                   \
    for (int dt = 0; dt < 8; ++dt) {                                                    \
      BVN[dt][0] = *(const bf16x8*)(vb + (size_t)(dt * 32 + l31) * NPIX + (MN) + hi * 8);        \
      BVN[dt][1] = *(const bf16x8*)(vb + (size_t)(dt * 32 + l31) * NPIX + (MN) + 16 + hi * 8);   \
    }                                                                                   \
    float p[16];                                                                        \
    _Pragma("unroll")                                                                   \
    for (int r = 0; r < 16; ++r) p[r] = __expf(s[r]);                                   \
    lsum += (((p[0] + p[1]) + (p[2] + p[3])) + ((p[4] + p[5]) + (p[6] + p[7]))) +       \
            (((p[8] + p[9]) + (p[10] + p[11])) + ((p[12] + p[13]) + (p[14] + p[15])));  \
    unsigned int c01, c23, c45, c67, c89, cAB, cCD, cEF;                                \
    asm("v_cvt_pk_bf16_f32 %0, %1, %2" : "=v"(c01) : "v"(p[0]), "v"(p[1]));             \
    asm("v_cvt_pk_bf16_f32 %0, %1, %2" : "=v"(c23) : "v"(p[2]), "v"(p[3]));             \
    asm("v_cvt_pk_bf16_f32 %0, %1, %2" : "=v"(c45) : "v"(p[4]), "v"(p[5]));             \
    asm("v_cvt_pk_bf16_f32 %0, %1, %2" : "=v"(c67) : "v"(p[6]), "v"(p[7]));             \
    asm("v_cvt_pk_bf16_f32 %0, %1, %2" : "=v"(c89) : "v"(p[8]), "v"(p[9]));             \
    asm("v_cvt_pk_bf16_f32 %0, %1, %2" : "=v"(cAB) : "v"(p[10]), "v"(p[11]));           \
    asm("v_cvt_pk_bf16_f32 %0, %1, %2" : "=v"(cCD) : "v"(p[12]), "v"(p[13]));           \
    asm("v_cvt_pk_bf16_f32 %0, %1, %2" : "=v"(cEF) : "v"(p[14]), "v"(p[15]));           \
    unsigned int f0a, f0c, f0b, f0d, f1a, f1c, f1b, f1d;                                \
    plswap(c01, c45, f0a, f0b);                                                         \
    plswap(c23, c67, f0c, f0d);                                                         \
    plswap(c89, cCD, f1a, f1b);                                                         \
    plswap(cAB, cEF, f1c, f1d);                                                         \
    union { unsigned int u[4]; bf16x8 v; } pa0, pa1;                                    \
    pa0.u[0] = f0a; pa0.u[1] = f0c; pa0.u[2] = f0b; pa0.u[3] = f0d;                     \
    pa1.u[0] = f1a; pa1.u[1] = f1c; pa1.u[2] = f1b; pa1.u[3] = f1d;                     \
    _Pragma("unroll")                                                                   \
    for (int dt = 0; dt < 8; ++dt)                                                      \
      accO[dt] = __builtin_amdgcn_mfma_f32_32x32x16_bf16(pa0.v, BV[dt][0], accO[dt], 0, 0, 0); \
    _Pragma("unroll")                                                                   \
    for (int dt = 0; dt < 8; ++dt)                                                      \
      accO[dt] = __builtin_amdgcn_mfma_f32_32x32x16_bf16(pa1.v, BV[dt][1], accO[dt], 0, 0, 0); \
  } while (0)

  for (int tt = 0; tt < 32; ++tt) {
    const int mb0 = mbase + tt * 64;
    const int mb1 = mb0 + 32;
    const int mb2 = mbase + ((tt * 64 + 64) & 2047);
    TILE_BODY(mb0, mb1, aFA, aFB, bVA, bVB);
    TILE_BODY(mb1, mb2, aFB, aFA, bVB, bVA);
  }
#undef TILE_BODY

  // ---- partial L: combine the two hi-halves (each q appears in lanes l31, l31+32) ----
  lsum += __shfl_xor(lsum, 32);
  if (lane < 32)
    Lbuf[ms * 16384 + b * 4096 + q0w + l31] = lsum;

  // ---- epilogue: per-wave LDS transpose to write PO[q][d] coalesced ----
#pragma unroll
  for (int dt = 0; dt < 8; ++dt) {
    int d = dt * 32 + l31;
#pragma unroll
    for (int r = 0; r < 16; ++r) {
      int ql = (r & 3) + 8 * (r >> 2) + 4 * hi;
      T[w][ql][d] = (__bf16)accO[dt][r];
    }
  }
  // same-wave RAW -> compiler inserts lgkmcnt; no barrier needed
  __bf16* poB = PO + ((size_t)(ms * 4 + b) * 4096 + q0w) * 256;
  const int qr = lane >> 1, dh = (lane & 1) * 128;
#pragma unroll
  for (int j = 0; j < 16; ++j) {
    bf16x8 v = *(const bf16x8*)(&T[w][qr][dh + j * 8]);
    *(bf16x8*)(poB + (size_t)qr * 256 + dh + j * 8) = v;
  }
}

// ---------- combine partials: obuf[q][d] = (PO0+PO1)*inv(L0+L1) ----------
// NOTE: obuf aliases PO half 0 — each thread reads its 16B of PO0/PO1 BEFORE
// writing the identical 16B address of obuf; no cross-thread overlap -> safe.
__global__ __launch_bounds__(256) void k_comb(const __bf16* __restrict__ PO,
                                              const float* __restrict__ Lbuf,
                                              __bf16* __restrict__ obuf) {
  int idx = blockIdx.x * 256 + threadIdx.x;  // 524288
  int row = idx >> 5, d0 = (idx & 31) * 8;
  float inv = 1.0f / (Lbuf[row] + Lbuf[16384 + row]);
  bf16x8 a = *(const bf16x8*)(PO + (size_t)row * 256 + d0);
  bf16x8 c = *(const bf16x8*)(PO + 4194304 + (size_t)row * 256 + d0);
  bf16x8 o;
#pragma unroll
  for (int j = 0; j < 8; ++j) o[j] = (__bf16)(((float)a[j] + (float)c[j]) * inv);
  *(bf16x8*)(obuf + (size_t)row * 256 + d0) = o;
}

// ---------- launch ----------
extern "C" void kernel_launch(void* const* d_in, const int* in_sizes, int n_in,
                              void* d_out, int out_size, void* d_ws, size_t ws_size,
                              hipStream_t stream) {
  const float* x = (const float*)d_in[0];
  const float* wf = (const float*)d_in[1];
  const float* bf_ = (const float*)d_in[2];
  const float* wg = (const float*)d_in[3];
  const float* bg_ = (const float*)d_in[4];
  const float* wh = (const float*)d_in[5];
  const float* bh_ = (const float*)d_in[6];
  const float* wo = (const float*)d_in[7];
  const float* bo = (const float*)d_in[8];
  const float* gamma = (const float*)d_in[9];
  const float* wc = (const float*)d_in[10];
  const float* bc = (const float*)d_in[11];
  const float* bns = (const float*)d_in[12];
  const float* bnb = (const float*)d_in[13];
  const float* bnm = (const float*)d_in[14];
  const float* bnv = (const float*)d_in[15];
  (void)in_sizes; (void)n_in; (void)out_size; (void)ws_size;

  char* ws = (char*)d_ws;
  __bf16* xb     = (__bf16*)(ws + 0);          // 16384*512*2  = 16,777,216
  __bf16* fg     = (__bf16*)(ws + 16777216);   // 16384*128*2  =  4,194,304
  __bf16* hvT    = (__bf16*)(ws + 20971520);   // 4*256*4096*2 =  8,388,608
  __bf16* PO     = (__bf16*)(ws + 29360128);   // 2*16384*256*2 = 16,777,216
  __bf16* obuf   = (__bf16*)(ws + 29360128);   // ALIASES PO half 0 (safe, see k_comb)
  float*  Lbuf   = (float*) (ws + 46137344);   // 2*16384*4    =    131,072
  __bf16* WfghT  = (__bf16*)(ws + 46268416);   // 384*512*2    =    393,216
  float*  bias384= (float*) (ws + 46661632);   // 384*4
  float*  Wow    = (float*) (ws + 46663168);   // 256*512*4    =    524,288
  __bf16* WcatT  = (__bf16*)(ws + 47187456);   // 512*768*2    =    786,432
  float*  biasF  = (float*) (ws + 47973888);   // 512*4  -> total 47,975,936 B
  float* out = (float*)d_out;

  hipLaunchKernelGGL(k_cvt, dim3(8192), dim3(256), 0, stream, x, xb, 2097152);
  hipLaunchKernelGGL(kp_wfgh, dim3(768), dim3(256), 0, stream, wf, wg, wh, WfghT);
  hipLaunchKernelGGL(kp_bias384, dim3(3), dim3(128), 0, stream, bf_, bg_, bh_, bias384);
  hipLaunchKernelGGL(kp_wow, dim3(512), dim3(256), 0, stream, wo, wc, Wow);
  hipLaunchKernelGGL(kp_wcat, dim3(1536), dim3(256), 0, stream, Wow, wc, gamma, bns, bnv, WcatT);
  hipLaunchKernelGGL(kp_biasF, dim3(2), dim3(256), 0, stream, bo, wc, bc, gamma, bns, bnb, bnm, bnv, biasF);
  hipLaunchKernelGGL((k_gemm<512, 384, 0>), dim3(128, 6), dim3(256), 0, stream,
                     xb, 512, 512, xb, 512, WfghT, bias384, (void*)fg, (void*)hvT);
  hipLaunchKernelGGL(k_attn, dim3(256), dim3(256), 0, stream, fg, hvT, PO, Lbuf);
  hipLaunchKernelGGL(k_comb, dim3(2048), dim3(256), 0, stream, PO, Lbuf, obuf);
  hipLaunchKernelGGL((k_gemm<768, 512, 1>), dim3(128, 8), dim3(256), 0, stream,
                     obuf, 256, 256, xb, 512, WcatT, biasF, (void*)out, nullptr);
}

// Round 6
// 345.916 us; speedup vs baseline: 1.0289x; 1.0289x over previous
//
#include <hip/hip_runtime.h>
#include <hip/hip_bf16.h>

typedef __bf16 bf16x8 __attribute__((ext_vector_type(8)));
typedef float f32x4 __attribute__((ext_vector_type(4)));

#define EPSBN 1e-3f

constexpr int NPIX = 4096;   // H*W
constexpr int D2 = 256;      // C/2

#define RAW_BARRIER() do { \
  asm volatile("s_waitcnt lgkmcnt(0)" ::: "memory"); \
  __builtin_amdgcn_s_barrier(); \
  asm volatile("" ::: "memory"); \
} while (0)

// ---------- x -> bf16 ----------
__global__ __launch_bounds__(256) void k_cvt(const float* __restrict__ x,
                                             __bf16* __restrict__ xb, int n4) {
  int i = blockIdx.x * 256 + threadIdx.x;
  if (i >= n4) return;
  float4 v = reinterpret_cast<const float4*>(x)[i];
  union { __bf16 h[4]; uint2 u; } o;
  o.h[0] = (__bf16)v.x; o.h[1] = (__bf16)v.y; o.h[2] = (__bf16)v.z; o.h[3] = (__bf16)v.w;
  reinterpret_cast<uint2*>(xb)[i] = o.u;
}

// ---------- weight precompute ----------
__global__ __launch_bounds__(256) void kp_wfgh(const float* __restrict__ wf,
                                               const float* __restrict__ wg,
                                               const float* __restrict__ wh,
                                               __bf16* __restrict__ WT) {
  int idx = blockIdx.x * 256 + threadIdx.x;  // < 384*512
  int c = idx >> 9, k = idx & 511;
  float v = (c < 64) ? wf[k * 64 + c] : (c < 128) ? wg[k * 64 + (c - 64)] : wh[k * 256 + (c - 128)];
  WT[idx] = (__bf16)v;
}

__global__ __launch_bounds__(128) void kp_bias384(const float* bf_, const float* bg_,
                                                  const float* bh_, float* bias) {
  int c = blockIdx.x * 128 + threadIdx.x;  // grid 3 -> 384
  bias[c] = (c < 64) ? bf_[c] : (c < 128) ? bg_[c - 64] : bh_[c - 128];
}

__global__ __launch_bounds__(256) void kp_wow(const float* __restrict__ wo,
                                              const float* __restrict__ wc,
                                              float* __restrict__ Wow) {
  int idx = blockIdx.x * 256 + threadIdx.x;  // 256*512
  int d = idx >> 9, c = idx & 511;
  float acc = 0.f;
  for (int j = 0; j < 512; ++j) acc += wo[d * 512 + j] * wc[j * 512 + c];
  Wow[idx] = acc;
}

__global__ __launch_bounds__(256) void kp_wcat(const float* __restrict__ Wow,
                                               const float* __restrict__ wc,
                                               const float* __restrict__ gamma,
                                               const float* __restrict__ bns,
                                               const float* __restrict__ bnv,
                                               __bf16* __restrict__ WT) {
  int idx = blockIdx.x * 256 + threadIdx.x;  // 512*768
  int c = idx / 768, k = idx % 768;
  float s = bns[c] * rsqrtf(bnv[c] + EPSBN);
  float v;
  if (k < 256) v = gamma[0] * Wow[k * 512 + c] * s;
  else { int kk = k - 256; v = (wc[kk * 512 + c] + wc[(512 + kk) * 512 + c]) * s; }
  WT[idx] = (__bf16)v;
}

__global__ __launch_bounds__(256) void kp_biasF(const float* bo, const float* wc, const float* bc,
                                                const float* gamma, const float* bns, const float* bnb,
                                                const float* bnm, const float* bnv, float* biasF) {
  int c = blockIdx.x * 256 + threadIdx.x;  // grid 2 -> 512
  float s = bns[c] * rsqrtf(bnv[c] + EPSBN);
  float acc = 0.f;
  for (int j = 0; j < 512; ++j) acc += bo[j] * wc[j * 512 + c];
  float pre = bc[c] + gamma[0] * acc;
  biasF[c] = (pre - bnm[c]) * s + bnb[c];
}

// ---------- generic MFMA GEMM: C[M][NC] = A[M][KT] @ WT^T + bias ----------
// MODE 0: out1 = fg [M][128] bf16 (cols<128), out2 = hvT [B][256][4096] bf16 (cols>=128, transposed)
// MODE 1: out1 = float out [M][NC], relu
template <int KT, int NC, int MODE>
__global__ __launch_bounds__(256) void k_gemm(const __bf16* __restrict__ A1, int k1, int lda1,
                                              const __bf16* __restrict__ A2, int lda2,
                                              const __bf16* __restrict__ WT,
                                              const float* __restrict__ bias,
                                              void* __restrict__ out1,
                                              void* __restrict__ out2) {
  __shared__ __bf16 As[128][72];
  __shared__ __bf16 Ws[64][72];
  const int m0 = blockIdx.x * 128, n0 = blockIdx.y * 64;
  const int tid = threadIdx.x, lane = tid & 63, w = tid >> 6;
  const int wr = w >> 1, wcl = w & 1;
  const int l15 = lane & 15, l4 = lane >> 4;
  f32x4 acc[4][2] = {};
  for (int ks = 0; ks < KT; ks += 64) {
    const __bf16* Asrc; int lda, kb;
    if (ks < k1) { Asrc = A1; lda = lda1; kb = ks; }
    else         { Asrc = A2; lda = lda2; kb = ks - k1; }
#pragma unroll
    for (int it = 0; it < 4; ++it) {
      int idx = it * 256 + tid, r = idx >> 3, ch = idx & 7;
      *(bf16x8*)(&As[r][ch * 8]) = *(const bf16x8*)(Asrc + (size_t)(m0 + r) * lda + kb + ch * 8);
    }
#pragma unroll
    for (int it = 0; it < 2; ++it) {
      int idx = it * 256 + tid, r = idx >> 3, ch = idx & 7;
      *(bf16x8*)(&Ws[r][ch * 8]) = *(const bf16x8*)(WT + (size_t)(n0 + r) * KT + ks + ch * 8);
    }
    __syncthreads();
#pragma unroll
    for (int kk = 0; kk < 2; ++kk) {
      int krd = kk * 32 + l4 * 8;
      bf16x8 av[4], bv[2];
#pragma unroll
      for (int mi = 0; mi < 4; ++mi) av[mi] = *(const bf16x8*)(&As[wr * 64 + mi * 16 + l15][krd]);
#pragma unroll
      for (int ni = 0; ni < 2; ++ni) bv[ni] = *(const bf16x8*)(&Ws[wcl * 32 + ni * 16 + l15][krd]);
#pragma unroll
      for (int mi = 0; mi < 4; ++mi)
#pragma unroll
        for (int ni = 0; ni < 2; ++ni)
          acc[mi][ni] = __builtin_amdgcn_mfma_f32_16x16x32_bf16(av[mi], bv[ni], acc[mi][ni], 0, 0, 0);
    }
    __syncthreads();
  }
#pragma unroll
  for (int mi = 0; mi < 4; ++mi)
#pragma unroll
    for (int ni = 0; ni < 2; ++ni) {
      int col = n0 + wcl * 32 + ni * 16 + l15;
      float bcol = bias[col];
      int row0 = m0 + wr * 64 + mi * 16 + l4 * 4;
      if (MODE == 1) {
        float* out = (float*)out1;
#pragma unroll
        for (int r = 0; r < 4; ++r)
          out[(size_t)(row0 + r) * NC + col] = fmaxf(acc[mi][ni][r] + bcol, 0.f);
      } else {
        if (col < 128) {
          __bf16* fg = (__bf16*)out1;
#pragma unroll
          for (int r = 0; r < 4; ++r)
            fg[(size_t)(row0 + r) * 128 + col] = (__bf16)(acc[mi][ni][r] + bcol);
        } else {
          __bf16* hvT = (__bf16*)out2;
          int bb = row0 >> 12, n = row0 & 4095;
          union { __bf16 h[4]; uint2 u; } pk;
#pragma unroll
          for (int r = 0; r < 4; ++r) pk.h[r] = (__bf16)(acc[mi][ni][r] + bcol);
          *(uint2*)(hvT + ((size_t)(bb * 256 + (col - 128))) * 4096 + n) = pk.u;
        }
      }
    }
}

// ---------- attention ----------
// fg: [B*4096][128] (f: cols 0..63 keys, g: cols 64..127 queries), hvT: [B][256][4096]
// Swapped QK^T (S^T = F G^T), no-max softmax p=exp(s), P exchanged via small LDS (dbuf),
// F/V fragments loaded global->reg directly (L2 resident), prefetched 1 iter ahead.
// QBLK=32 (vs R2's 64): grid 512 -> 2 blocks/CU so barrier stalls overlap across blocks.
__global__ __launch_bounds__(512, 2) void k_attn(const __bf16* __restrict__ fg,
                                                 const __bf16* __restrict__ hvT,
                                                 __bf16* __restrict__ obuf) {
  __shared__ __bf16 PsT[2][32][136];
  __shared__ float Lp[8][32];
  // XCD swizzle: batch b -> 2 XCDs, so each XCD's L2 caches one batch's F+V (2.5MB < 4MB)
  const int id = blockIdx.x;
  const int xcd = id & 7, i2 = id >> 3;
  const int b = xcd >> 1;
  const int q0 = (i2 * 2 + (xcd & 1)) * 32;
  const int tid = threadIdx.x, w = tid >> 6, lane = tid & 63;
  const int l15 = lane & 15, l4 = lane >> 4;
  const __bf16* fgb = fg + (size_t)b * NPIX * 128;
  const __bf16* vb = hvT + (size_t)b * D2 * NPIX;

  // preload query fragments bG[qt][kk]
  bf16x8 bG[2][2];
#pragma unroll
  for (int qt = 0; qt < 2; ++qt)
#pragma unroll
    for (int kk = 0; kk < 2; ++kk)
      bG[qt][kk] = *(const bf16x8*)(fgb + (size_t)(q0 + qt * 16 + l15) * 128 + 64 + kk * 32 + l4 * 8);

  // prologue prefetch: key fragments (this wave's m-slice) and V fragments (this wave's d-slice)
  bf16x8 aF[2], bV[2][4];
#pragma unroll
  for (int kk = 0; kk < 2; ++kk)
    aF[kk] = *(const bf16x8*)(fgb + (size_t)(w * 16 + l15) * 128 + kk * 32 + l4 * 8);
#pragma unroll
  for (int dj = 0; dj < 2; ++dj)
#pragma unroll
    for (int k4 = 0; k4 < 4; ++k4)
      bV[dj][k4] = *(const bf16x8*)(vb + (size_t)(w * 32 + dj * 16 + l15) * NPIX + k4 * 32 + l4 * 8);

  f32x4 accO[2][2] = {};
  float lsum[2] = {0.f, 0.f};

  for (int t = 0; t < 32; ++t) {
    const int mn = ((t + 1) * 128) & (NPIX - 1);  // next m-tile (wraps on last iter)
    const int bufi = t & 1;
    // ---- QK^T (swapped): S^T[m][q], this wave's 16-m slice, all 32 q ----
    f32x4 s[2];
#pragma unroll
    for (int qt = 0; qt < 2; ++qt) {
      s[qt] = (f32x4){0.f, 0.f, 0.f, 0.f};
#pragma unroll
      for (int kk = 0; kk < 2; ++kk)
        s[qt] = __builtin_amdgcn_mfma_f32_16x16x32_bf16(aF[kk], bG[qt][kk], s[qt], 0, 0, 0);
    }
    // prefetch next aF
    bf16x8 aFn[2];
#pragma unroll
    for (int kk = 0; kk < 2; ++kk)
      aFn[kk] = *(const bf16x8*)(fgb + (size_t)(mn + w * 16 + l15) * 128 + kk * 32 + l4 * 8);
    // exp + pack pairs + write PsT[q][m]
#pragma unroll
    for (int qt = 0; qt < 2; ++qt) {
      float p0 = __expf(s[qt][0]), p1 = __expf(s[qt][1]);
      float p2 = __expf(s[qt][2]), p3 = __expf(s[qt][3]);
      lsum[qt] += (p0 + p1) + (p2 + p3);
      union { __bf16 h[2]; uint u; } w0, w1;
      w0.h[0] = (__bf16)p0; w0.h[1] = (__bf16)p1;
      w1.h[0] = (__bf16)p2; w1.h[1] = (__bf16)p3;
      *(uint*)(&PsT[bufi][qt * 16 + l15][w * 16 + l4 * 4]) = w0.u;
      *(uint*)(&PsT[bufi][qt * 16 + l15][w * 16 + l4 * 4 + 2]) = w1.u;
    }
    RAW_BARRIER();  // PsT ready; vmcnt NOT drained (prefetches stay in flight)
    // ---- PV: O[q][d-slice], P from LDS, V from regs ----
#pragma unroll
    for (int qt = 0; qt < 2; ++qt) {
      bf16x8 aP[4];
#pragma unroll
      for (int k4 = 0; k4 < 4; ++k4)
        aP[k4] = *(const bf16x8*)(&PsT[bufi][qt * 16 + l15][k4 * 32 + l4 * 8]);
#pragma unroll
      for (int dj = 0; dj < 2; ++dj)
#pragma unroll
        for (int k4 = 0; k4 < 4; ++k4)
          accO[qt][dj] = __builtin_amdgcn_mfma_f32_16x16x32_bf16(aP[k4], bV[dj][k4], accO[qt][dj], 0, 0, 0);
    }
    // prefetch next bV
#pragma unroll
    for (int dj = 0; dj < 2; ++dj)
#pragma unroll
      for (int k4 = 0; k4 < 4; ++k4)
        bV[dj][k4] = *(const bf16x8*)(vb + (size_t)(w * 32 + dj * 16 + l15) * NPIX + mn + k4 * 32 + l4 * 8);
    aF[0] = aFn[0]; aF[1] = aFn[1];
  }

  // ---- denominators: reduce lsum over l4 groups, then over waves via LDS ----
#pragma unroll
  for (int qt = 0; qt < 2; ++qt) {
    float v = lsum[qt];
    v += __shfl_xor(v, 16); v += __shfl_xor(v, 32);
    lsum[qt] = v;
  }
  if (l4 == 0) {
#pragma unroll
    for (int qt = 0; qt < 2; ++qt) Lp[w][qt * 16 + l15] = lsum[qt];
  }
  __syncthreads();
  float inv[2][4];
#pragma unroll
  for (int qt = 0; qt < 2; ++qt)
#pragma unroll
    for (int r = 0; r < 4; ++r) {
      int q = qt * 16 + l4 * 4 + r;
      float lt = 0.f;
#pragma unroll
      for (int ww = 0; ww < 8; ++ww) lt += Lp[ww][q];
      inv[qt][r] = 1.0f / lt;
    }
  __bf16* ob = obuf + ((size_t)b * NPIX + q0) * D2;
#pragma unroll
  for (int qt = 0; qt < 2; ++qt)
#pragma unroll
    for (int dj = 0; dj < 2; ++dj)
#pragma unroll
      for (int r = 0; r < 4; ++r)
        ob[(size_t)(qt * 16 + l4 * 4 + r) * D2 + w * 32 + dj * 16 + l15] =
            (__bf16)(accO[qt][dj][r] * inv[qt][r]);
}

// ---------- launch ----------
extern "C" void kernel_launch(void* const* d_in, const int* in_sizes, int n_in,
                              void* d_out, int out_size, void* d_ws, size_t ws_size,
                              hipStream_t stream) {
  const float* x = (const float*)d_in[0];
  const float* wf = (const float*)d_in[1];
  const float* bf_ = (const float*)d_in[2];
  const float* wg = (const float*)d_in[3];
  const float* bg_ = (const float*)d_in[4];
  const float* wh = (const float*)d_in[5];
  const float* bh_ = (const float*)d_in[6];
  const float* wo = (const float*)d_in[7];
  const float* bo = (const float*)d_in[8];
  const float* gamma = (const float*)d_in[9];
  const float* wc = (const float*)d_in[10];
  const float* bc = (const float*)d_in[11];
  const float* bns = (const float*)d_in[12];
  const float* bnb = (const float*)d_in[13];
  const float* bnm = (const float*)d_in[14];
  const float* bnv = (const float*)d_in[15];
  (void)in_sizes; (void)n_in; (void)out_size; (void)ws_size;

  char* ws = (char*)d_ws;
  __bf16* xb     = (__bf16*)(ws + 0);          // 16384*512*2  = 16,777,216
  __bf16* fg     = (__bf16*)(ws + 16777216);   // 16384*128*2  =  4,194,304
  __bf16* hvT    = (__bf16*)(ws + 20971520);   // 4*256*4096*2 =  8,388,608
  __bf16* obuf   = (__bf16*)(ws + 29360128);   // 16384*256*2  =  8,388,608
  __bf16* WfghT  = (__bf16*)(ws + 37748736);   // 384*512*2    =    393,216
  float*  bias384= (float*) (ws + 38141952);   // 384*4
  float*  Wow    = (float*) (ws + 38143488);   // 256*512*4    =    524,288
  __bf16* WcatT  = (__bf16*)(ws + 38667776);   // 512*768*2    =    786,432
  float*  biasF  = (float*) (ws + 39454208);   // 512*4  -> total ~39.5 MB
  float* out = (float*)d_out;

  hipLaunchKernelGGL(k_cvt, dim3(8192), dim3(256), 0, stream, x, xb, 2097152);
  hipLaunchKernelGGL(kp_wfgh, dim3(768), dim3(256), 0, stream, wf, wg, wh, WfghT);
  hipLaunchKernelGGL(kp_bias384, dim3(3), dim3(128), 0, stream, bf_, bg_, bh_, bias384);
  hipLaunchKernelGGL(kp_wow, dim3(512), dim3(256), 0, stream, wo, wc, Wow);
  hipLaunchKernelGGL(kp_wcat, dim3(1536), dim3(256), 0, stream, Wow, wc, gamma, bns, bnv, WcatT);
  hipLaunchKernelGGL(kp_biasF, dim3(2), dim3(256), 0, stream, bo, wc, bc, gamma, bns, bnb, bnm, bnv, biasF);
  hipLaunchKernelGGL((k_gemm<512, 384, 0>), dim3(128, 6), dim3(256), 0, stream,
                     xb, 512, 512, xb, 512, WfghT, bias384, (void*)fg, (void*)hvT);
  hipLaunchKernelGGL(k_attn, dim3(512), dim3(512), 0, stream, fg, hvT, obuf);
  hipLaunchKernelGGL((k_gemm<768, 512, 1>), dim3(128, 8), dim3(256), 0, stream,
                     obuf, 256, 256, xb, 512, WcatT, biasF, (void*)out, nullptr);
}

// Round 7
// 283.590 us; speedup vs baseline: 1.2551x; 1.2198x over previous
//
#include <hip/hip_runtime.h>
#include <hip/hip_bf16.h>

typedef __bf16 bf16x8 __attribute__((ext_vector_type(8)));
typedef float f32x4 __attribute__((ext_vector_type(4)));

#define EPSBN 1e-3f

constexpr int NPIX = 4096;   // H*W
constexpr int D2 = 256;      // C/2

#define RAW_BARRIER() do { \
  asm volatile("s_waitcnt lgkmcnt(0)" ::: "memory"); \
  __builtin_amdgcn_s_barrier(); \
  asm volatile("" ::: "memory"); \
} while (0)

// ---------- x -> bf16 ----------
__global__ __launch_bounds__(256) void k_cvt(const float* __restrict__ x,
                                             __bf16* __restrict__ xb, int n4) {
  int i = blockIdx.x * 256 + threadIdx.x;
  if (i >= n4) return;
  float4 v = reinterpret_cast<const float4*>(x)[i];
  union { __bf16 h[4]; uint2 u; } o;
  o.h[0] = (__bf16)v.x; o.h[1] = (__bf16)v.y; o.h[2] = (__bf16)v.z; o.h[3] = (__bf16)v.w;
  reinterpret_cast<uint2*>(xb)[i] = o.u;
}

// ---------- weight precompute ----------
__global__ __launch_bounds__(256) void kp_wfgh(const float* __restrict__ wf,
                                               const float* __restrict__ wg,
                                               const float* __restrict__ wh,
                                               __bf16* __restrict__ WT) {
  int idx = blockIdx.x * 256 + threadIdx.x;  // < 384*512
  int c = idx >> 9, k = idx & 511;
  float v = (c < 64) ? wf[k * 64 + c] : (c < 128) ? wg[k * 64 + (c - 64)] : wh[k * 256 + (c - 128)];
  WT[idx] = (__bf16)v;
}

__global__ __launch_bounds__(128) void kp_bias384(const float* bf_, const float* bg_,
                                                  const float* bh_, float* bias) {
  int c = blockIdx.x * 128 + threadIdx.x;  // grid 3 -> 384
  bias[c] = (c < 64) ? bf_[c] : (c < 128) ? bg_[c - 64] : bh_[c - 128];
}

// Wow[d][c] = sum_j wo[d][j] * wc[j][c]  — 4-way ILP + float4 on row-major wo
__global__ __launch_bounds__(256) void kp_wow(const float* __restrict__ wo,
                                              const float* __restrict__ wc,
                                              float* __restrict__ Wow) {
  int idx = blockIdx.x * 256 + threadIdx.x;  // 256*512
  int d = idx >> 9, c = idx & 511;
  float a0 = 0.f, a1 = 0.f, a2 = 0.f, a3 = 0.f;
  for (int j = 0; j < 512; j += 4) {
    float4 w4 = *reinterpret_cast<const float4*>(wo + d * 512 + j);
    a0 += w4.x * wc[(size_t)j * 512 + c];
    a1 += w4.y * wc[(size_t)(j + 1) * 512 + c];
    a2 += w4.z * wc[(size_t)(j + 2) * 512 + c];
    a3 += w4.w * wc[(size_t)(j + 3) * 512 + c];
  }
  Wow[idx] = (a0 + a1) + (a2 + a3);
}

__global__ __launch_bounds__(256) void kp_wcat(const float* __restrict__ Wow,
                                               const float* __restrict__ wc,
                                               const float* __restrict__ gamma,
                                               const float* __restrict__ bns,
                                               const float* __restrict__ bnv,
                                               __bf16* __restrict__ WT) {
  int idx = blockIdx.x * 256 + threadIdx.x;  // 512*768
  int c = idx / 768, k = idx % 768;
  float s = bns[c] * rsqrtf(bnv[c] + EPSBN);
  float v;
  if (k < 256) v = gamma[0] * Wow[k * 512 + c] * s;
  else { int kk = k - 256; v = (wc[kk * 512 + c] + wc[(512 + kk) * 512 + c]) * s; }
  WT[idx] = (__bf16)v;
}

__global__ __launch_bounds__(256) void kp_biasF(const float* bo, const float* wc, const float* bc,
                                                const float* gamma, const float* bns, const float* bnb,
                                                const float* bnm, const float* bnv, float* biasF) {
  int c = blockIdx.x * 256 + threadIdx.x;  // grid 2 -> 512
  float s = bns[c] * rsqrtf(bnv[c] + EPSBN);
  float a0 = 0.f, a1 = 0.f, a2 = 0.f, a3 = 0.f;
  for (int j = 0; j < 512; j += 4) {
    a0 += bo[j] * wc[(size_t)j * 512 + c];
    a1 += bo[j + 1] * wc[(size_t)(j + 1) * 512 + c];
    a2 += bo[j + 2] * wc[(size_t)(j + 2) * 512 + c];
    a3 += bo[j + 3] * wc[(size_t)(j + 3) * 512 + c];
  }
  float pre = bc[c] + gamma[0] * ((a0 + a1) + (a2 + a3));
  biasF[c] = (pre - bnm[c]) * s + bnb[c];
}

// ---------- generic MFMA GEMM: C[M][NC] = A[M][KT] @ WT^T + bias ----------
// MODE 0: out1 = fg [M][128] bf16 (cols<128), out2 = hvT [B][256][4096] bf16 (cols>=128, transposed)
// MODE 1: out1 = float out [M][NC], relu
template <int KT, int NC, int MODE>
__global__ __launch_bounds__(256) void k_gemm(const __bf16* __restrict__ A1, int k1, int lda1,
                                              const __bf16* __restrict__ A2, int lda2,
                                              const __bf16* __restrict__ WT,
                                              const float* __restrict__ bias,
                                              void* __restrict__ out1,
                                              void* __restrict__ out2) {
  __shared__ __bf16 As[128][72];
  __shared__ __bf16 Ws[64][72];
  const int m0 = blockIdx.x * 128, n0 = blockIdx.y * 64;
  const int tid = threadIdx.x, lane = tid & 63, w = tid >> 6;
  const int wr = w >> 1, wcl = w & 1;
  const int l15 = lane & 15, l4 = lane >> 4;
  f32x4 acc[4][2] = {};
  for (int ks = 0; ks < KT; ks += 64) {
    const __bf16* Asrc; int lda, kb;
    if (ks < k1) { Asrc = A1; lda = lda1; kb = ks; }
    else         { Asrc = A2; lda = lda2; kb = ks - k1; }
#pragma unroll
    for (int it = 0; it < 4; ++it) {
      int idx = it * 256 + tid, r = idx >> 3, ch = idx & 7;
      *(bf16x8*)(&As[r][ch * 8]) = *(const bf16x8*)(Asrc + (size_t)(m0 + r) * lda + kb + ch * 8);
    }
#pragma unroll
    for (int it = 0; it < 2; ++it) {
      int idx = it * 256 + tid, r = idx >> 3, ch = idx & 7;
      *(bf16x8*)(&Ws[r][ch * 8]) = *(const bf16x8*)(WT + (size_t)(n0 + r) * KT + ks + ch * 8);
    }
    __syncthreads();
#pragma unroll
    for (int kk = 0; kk < 2; ++kk) {
      int krd = kk * 32 + l4 * 8;
      bf16x8 av[4], bv[2];
#pragma unroll
      for (int mi = 0; mi < 4; ++mi) av[mi] = *(const bf16x8*)(&As[wr * 64 + mi * 16 + l15][krd]);
#pragma unroll
      for (int ni = 0; ni < 2; ++ni) bv[ni] = *(const bf16x8*)(&Ws[wcl * 32 + ni * 16 + l15][krd]);
#pragma unroll
      for (int mi = 0; mi < 4; ++mi)
#pragma unroll
        for (int ni = 0; ni < 2; ++ni)
          acc[mi][ni] = __builtin_amdgcn_mfma_f32_16x16x32_bf16(av[mi], bv[ni], acc[mi][ni], 0, 0, 0);
    }
    __syncthreads();
  }
#pragma unroll
  for (int mi = 0; mi < 4; ++mi)
#pragma unroll
    for (int ni = 0; ni < 2; ++ni) {
      int col = n0 + wcl * 32 + ni * 16 + l15;
      float bcol = bias[col];
      int row0 = m0 + wr * 64 + mi * 16 + l4 * 4;
      if (MODE == 1) {
        float* out = (float*)out1;
#pragma unroll
        for (int r = 0; r < 4; ++r)
          out[(size_t)(row0 + r) * NC + col] = fmaxf(acc[mi][ni][r] + bcol, 0.f);
      } else {
        if (col < 128) {
          __bf16* fg = (__bf16*)out1;
#pragma unroll
          for (int r = 0; r < 4; ++r)
            fg[(size_t)(row0 + r) * 128 + col] = (__bf16)(acc[mi][ni][r] + bcol);
        } else {
          __bf16* hvT = (__bf16*)out2;
          int bb = row0 >> 12, n = row0 & 4095;
          union { __bf16 h[4]; uint2 u; } pk;
#pragma unroll
          for (int r = 0; r < 4; ++r) pk.h[r] = (__bf16)(acc[mi][ni][r] + bcol);
          *(uint2*)(hvT + ((size_t)(bb * 256 + (col - 128))) * 4096 + n) = pk.u;
        }
      }
    }
}

// ---------- attention ----------
// fg: [B*4096][128] (f cols 0..63 keys, g cols 64..127 queries), hvT: [B][256][4096]
// R2 structure (QBLK=64, proven) + d-split across 2 blocks: each block owns a
// 128-wide d-half (wave w -> 16 d-cols), QK^T recomputed per half (cheap).
// Per-block V traffic halves -> total V stream stays at R2's 512MB while the
// grid doubles to 512 -> 2 blocks/CU, 4 waves/SIMD of latency hiding.
__global__ __launch_bounds__(512, 4) void k_attn(const __bf16* __restrict__ fg,
                                                 const __bf16* __restrict__ hvT,
                                                 __bf16* __restrict__ obuf) {
  __shared__ __bf16 PsT[2][64][136];
  __shared__ float Lp[8][64];
  // XCD swizzle: batch b -> 2 XCDs (F+V slab L2-resident per XCD)
  const int id = blockIdx.x;
  const int xcd = id & 7, i2 = id >> 3;   // i2: 0..63
  const int b = xcd >> 1;
  const int dh = i2 & 1;                  // d-half
  const int q0 = ((i2 >> 1) * 2 + (xcd & 1)) * 64;
  const int tid = threadIdx.x, w = tid >> 6, lane = tid & 63;
  const int l15 = lane & 15, l4 = lane >> 4;
  const int dcol = dh * 128 + w * 16;     // this wave's 16 d-cols
  const __bf16* fgb = fg + (size_t)b * NPIX * 128;
  const __bf16* vb = hvT + (size_t)b * D2 * NPIX;

  // query fragments (resident)
  bf16x8 bG[4][2];
#pragma unroll
  for (int qt = 0; qt < 4; ++qt)
#pragma unroll
    for (int kk = 0; kk < 2; ++kk)
      bG[qt][kk] = *(const bf16x8*)(fgb + (size_t)(q0 + qt * 16 + l15) * 128 + 64 + kk * 32 + l4 * 8);

  // prologue prefetch: key fragments (this wave's m-slice) and V fragments (this wave's d-cols)
  bf16x8 aF[2], bV[4];
#pragma unroll
  for (int kk = 0; kk < 2; ++kk)
    aF[kk] = *(const bf16x8*)(fgb + (size_t)(w * 16 + l15) * 128 + kk * 32 + l4 * 8);
#pragma unroll
  for (int k4 = 0; k4 < 4; ++k4)
    bV[k4] = *(const bf16x8*)(vb + (size_t)(dcol + l15) * NPIX + k4 * 32 + l4 * 8);

  f32x4 accO[4] = {};
  float lsum[4] = {0.f, 0.f, 0.f, 0.f};

  for (int t = 0; t < 32; ++t) {
    const int mn = ((t + 1) * 128) & (NPIX - 1);  // next m-tile (wraps on last iter)
    const int bufi = t & 1;
    // ---- QK^T (swapped): S^T[m][q], this wave's 16-m slice, all 64 q ----
    f32x4 s[4];
#pragma unroll
    for (int qt = 0; qt < 4; ++qt) {
      s[qt] = (f32x4){0.f, 0.f, 0.f, 0.f};
#pragma unroll
      for (int kk = 0; kk < 2; ++kk)
        s[qt] = __builtin_amdgcn_mfma_f32_16x16x32_bf16(aF[kk], bG[qt][kk], s[qt], 0, 0, 0);
    }
    // prefetch next aF
    bf16x8 aFn[2];
#pragma unroll
    for (int kk = 0; kk < 2; ++kk)
      aFn[kk] = *(const bf16x8*)(fgb + (size_t)(mn + w * 16 + l15) * 128 + kk * 32 + l4 * 8);
    // exp + pack pairs + write PsT[q][m]
#pragma unroll
    for (int qt = 0; qt < 4; ++qt) {
      float p0 = __expf(s[qt][0]), p1 = __expf(s[qt][1]);
      float p2 = __expf(s[qt][2]), p3 = __expf(s[qt][3]);
      lsum[qt] += (p0 + p1) + (p2 + p3);
      union { __bf16 h[2]; uint u; } w0, w1;
      w0.h[0] = (__bf16)p0; w0.h[1] = (__bf16)p1;
      w1.h[0] = (__bf16)p2; w1.h[1] = (__bf16)p3;
      *(uint*)(&PsT[bufi][qt * 16 + l15][w * 16 + l4 * 4]) = w0.u;
      *(uint*)(&PsT[bufi][qt * 16 + l15][w * 16 + l4 * 4 + 2]) = w1.u;
    }
    RAW_BARRIER();  // PsT ready; vmcnt NOT drained (prefetches stay in flight)
    // ---- PV: O[q][16 d-cols], P from LDS, V from regs ----
#pragma unroll
    for (int qt = 0; qt < 4; ++qt) {
      bf16x8 aP[4];
#pragma unroll
      for (int k4 = 0; k4 < 4; ++k4)
        aP[k4] = *(const bf16x8*)(&PsT[bufi][qt * 16 + l15][k4 * 32 + l4 * 8]);
#pragma unroll
      for (int k4 = 0; k4 < 4; ++k4)
        accO[qt] = __builtin_amdgcn_mfma_f32_16x16x32_bf16(aP[k4], bV[k4], accO[qt], 0, 0, 0);
    }
    // prefetch next bV
#pragma unroll
    for (int k4 = 0; k4 < 4; ++k4)
      bV[k4] = *(const bf16x8*)(vb + (size_t)(dcol + l15) * NPIX + mn + k4 * 32 + l4 * 8);
    aF[0] = aFn[0]; aF[1] = aFn[1];
  }

  // ---- denominators: reduce lsum over l4 groups, then over waves via LDS ----
#pragma unroll
  for (int qt = 0; qt < 4; ++qt) {
    float v = lsum[qt];
    v += __shfl_xor(v, 16); v += __shfl_xor(v, 32);
    lsum[qt] = v;
  }
  if (l4 == 0) {
#pragma unroll
    for (int qt = 0; qt < 4; ++qt) Lp[w][qt * 16 + l15] = lsum[qt];
  }
  __syncthreads();
  float inv[4][4];
#pragma unroll
  for (int qt = 0; qt < 4; ++qt)
#pragma unroll
    for (int r = 0; r < 4; ++r) {
      int q = qt * 16 + l4 * 4 + r;
      float lt = 0.f;
#pragma unroll
      for (int ww = 0; ww < 8; ++ww) lt += Lp[ww][q];
      inv[qt][r] = 1.0f / lt;
    }
  __bf16* ob = obuf + ((size_t)b * NPIX + q0) * D2;
#pragma unroll
  for (int qt = 0; qt < 4; ++qt)
#pragma unroll
    for (int r = 0; r < 4; ++r)
      ob[(size_t)(qt * 16 + l4 * 4 + r) * D2 + dcol + l15] =
          (__bf16)(accO[qt][r] * inv[qt][r]);
}

// ---------- launch ----------
extern "C" void kernel_launch(void* const* d_in, const int* in_sizes, int n_in,
                              void* d_out, int out_size, void* d_ws, size_t ws_size,
                              hipStream_t stream) {
  const float* x = (const float*)d_in[0];
  const float* wf = (const float*)d_in[1];
  const float* bf_ = (const float*)d_in[2];
  const float* wg = (const float*)d_in[3];
  const float* bg_ = (const float*)d_in[4];
  const float* wh = (const float*)d_in[5];
  const float* bh_ = (const float*)d_in[6];
  const float* wo = (const float*)d_in[7];
  const float* bo = (const float*)d_in[8];
  const float* gamma = (const float*)d_in[9];
  const float* wc = (const float*)d_in[10];
  const float* bc = (const float*)d_in[11];
  const float* bns = (const float*)d_in[12];
  const float* bnb = (const float*)d_in[13];
  const float* bnm = (const float*)d_in[14];
  const float* bnv = (const float*)d_in[15];
  (void)in_sizes; (void)n_in; (void)out_size; (void)ws_size;

  char* ws = (char*)d_ws;
  __bf16* xb     = (__bf16*)(ws + 0);          // 16384*512*2  = 16,777,216
  __bf16* fg     = (__bf16*)(ws + 16777216);   // 16384*128*2  =  4,194,304
  __bf16* hvT    = (__bf16*)(ws + 20971520);   // 4*256*4096*2 =  8,388,608
  __bf16* obuf   = (__bf16*)(ws + 29360128);   // 16384*256*2  =  8,388,608
  __bf16* WfghT  = (__bf16*)(ws + 37748736);   // 384*512*2    =    393,216
  float*  bias384= (float*) (ws + 38141952);   // 384*4
  float*  Wow    = (float*) (ws + 38143488);   // 256*512*4    =    524,288
  __bf16* WcatT  = (__bf16*)(ws + 38667776);   // 512*768*2    =    786,432
  float*  biasF  = (float*) (ws + 39454208);   // 512*4  -> total ~39.5 MB
  float* out = (float*)d_out;

  hipLaunchKernelGGL(k_cvt, dim3(8192), dim3(256), 0, stream, x, xb, 2097152);
  hipLaunchKernelGGL(kp_wfgh, dim3(768), dim3(256), 0, stream, wf, wg, wh, WfghT);
  hipLaunchKernelGGL(kp_bias384, dim3(3), dim3(128), 0, stream, bf_, bg_, bh_, bias384);
  hipLaunchKernelGGL(kp_wow, dim3(512), dim3(256), 0, stream, wo, wc, Wow);
  hipLaunchKernelGGL(kp_wcat, dim3(1536), dim3(256), 0, stream, Wow, wc, gamma, bns, bnv, WcatT);
  hipLaunchKernelGGL(kp_biasF, dim3(2), dim3(256), 0, stream, bo, wc, bc, gamma, bns, bnb, bnm, bnv, biasF);
  hipLaunchKernelGGL((k_gemm<512, 384, 0>), dim3(128, 6), dim3(256), 0, stream,
                     xb, 512, 512, xb, 512, WfghT, bias384, (void*)fg, (void*)hvT);
  hipLaunchKernelGGL(k_attn, dim3(512), dim3(512), 0, stream, fg, hvT, obuf);
  hipLaunchKernelGGL((k_gemm<768, 512, 1>), dim3(128, 8), dim3(256), 0, stream,
                     obuf, 256, 256, xb, 512, WcatT, biasF, (void*)out, nullptr);
}

// Round 8
// 269.668 us; speedup vs baseline: 1.3199x; 1.0516x over previous
//
#include <hip/hip_runtime.h>
#include <hip/hip_bf16.h>

typedef __bf16 bf16x8 __attribute__((ext_vector_type(8)));
typedef float f32x4 __attribute__((ext_vector_type(4)));

#define EPSBN 1e-3f

constexpr int NPIX = 4096;   // H*W
constexpr int D2 = 256;      // C/2

#define RAW_BARRIER() do { \
  asm volatile("s_waitcnt lgkmcnt(0)" ::: "memory"); \
  __builtin_amdgcn_s_barrier(); \
  asm volatile("" ::: "memory"); \
} while (0)

// ---------- x -> bf16 ----------
__global__ __launch_bounds__(256) void k_cvt(const float* __restrict__ x,
                                             __bf16* __restrict__ xb, int n4) {
  int i = blockIdx.x * 256 + threadIdx.x;
  if (i >= n4) return;
  float4 v = reinterpret_cast<const float4*>(x)[i];
  union { __bf16 h[4]; uint2 u; } o;
  o.h[0] = (__bf16)v.x; o.h[1] = (__bf16)v.y; o.h[2] = (__bf16)v.z; o.h[3] = (__bf16)v.w;
  reinterpret_cast<uint2*>(xb)[i] = o.u;
}

// ---------- weight precompute ----------
__global__ __launch_bounds__(256) void kp_wfgh(const float* __restrict__ wf,
                                               const float* __restrict__ wg,
                                               const float* __restrict__ wh,
                                               __bf16* __restrict__ WT) {
  int idx = blockIdx.x * 256 + threadIdx.x;  // < 384*512
  int c = idx >> 9, k = idx & 511;
  float v = (c < 64) ? wf[k * 64 + c] : (c < 128) ? wg[k * 64 + (c - 64)] : wh[k * 256 + (c - 128)];
  WT[idx] = (__bf16)v;
}

__global__ __launch_bounds__(128) void kp_bias384(const float* bf_, const float* bg_,
                                                  const float* bh_, float* bias) {
  int c = blockIdx.x * 128 + threadIdx.x;  // grid 3 -> 384
  bias[c] = (c < 64) ? bf_[c] : (c < 128) ? bg_[c - 64] : bh_[c - 128];
}

// Wow[d][c] = sum_j wo[d][j] * wc[j][c]  — 4-way ILP + float4 on row-major wo
__global__ __launch_bounds__(256) void kp_wow(const float* __restrict__ wo,
                                              const float* __restrict__ wc,
                                              float* __restrict__ Wow) {
  int idx = blockIdx.x * 256 + threadIdx.x;  // 256*512
  int d = idx >> 9, c = idx & 511;
  float a0 = 0.f, a1 = 0.f, a2 = 0.f, a3 = 0.f;
  for (int j = 0; j < 512; j += 4) {
    float4 w4 = *reinterpret_cast<const float4*>(wo + d * 512 + j);
    a0 += w4.x * wc[(size_t)j * 512 + c];
    a1 += w4.y * wc[(size_t)(j + 1) * 512 + c];
    a2 += w4.z * wc[(size_t)(j + 2) * 512 + c];
    a3 += w4.w * wc[(size_t)(j + 3) * 512 + c];
  }
  Wow[idx] = (a0 + a1) + (a2 + a3);
}

__global__ __launch_bounds__(256) void kp_wcat(const float* __restrict__ Wow,
                                               const float* __restrict__ wc,
                                               const float* __restrict__ gamma,
                                               const float* __restrict__ bns,
                                               const float* __restrict__ bnv,
                                               __bf16* __restrict__ WT) {
  int idx = blockIdx.x * 256 + threadIdx.x;  // 512*768
  int c = idx / 768, k = idx % 768;
  float s = bns[c] * rsqrtf(bnv[c] + EPSBN);
  float v;
  if (k < 256) v = gamma[0] * Wow[k * 512 + c] * s;
  else { int kk = k - 256; v = (wc[kk * 512 + c] + wc[(512 + kk) * 512 + c]) * s; }
  WT[idx] = (__bf16)v;
}

__global__ __launch_bounds__(256) void kp_biasF(const float* bo, const float* wc, const float* bc,
                                                const float* gamma, const float* bns, const float* bnb,
                                                const float* bnm, const float* bnv, float* biasF) {
  int c = blockIdx.x * 256 + threadIdx.x;  // grid 2 -> 512
  float s = bns[c] * rsqrtf(bnv[c] + EPSBN);
  float a0 = 0.f, a1 = 0.f, a2 = 0.f, a3 = 0.f;
  for (int j = 0; j < 512; j += 4) {
    a0 += bo[j] * wc[(size_t)j * 512 + c];
    a1 += bo[j + 1] * wc[(size_t)(j + 1) * 512 + c];
    a2 += bo[j + 2] * wc[(size_t)(j + 2) * 512 + c];
    a3 += bo[j + 3] * wc[(size_t)(j + 3) * 512 + c];
  }
  float pre = bc[c] + gamma[0] * ((a0 + a1) + (a2 + a3));
  biasF[c] = (pre - bnm[c]) * s + bnb[c];
}

// ---------- generic MFMA GEMM: C[M][NC] = A[M][KT] @ WT^T + bias ----------
// MODE 0: out1 = fg [M][128] bf16 (cols<128), out2 = hvT [B][256][4096] (cols>=128,
//         transposed via LDS staging -> coalesced 128B row writes)
// MODE 1: out1 = float out [M][NC], relu
template <int KT, int NC, int MODE>
__global__ __launch_bounds__(256) void k_gemm(const __bf16* __restrict__ A1, int k1, int lda1,
                                              const __bf16* __restrict__ A2, int lda2,
                                              const __bf16* __restrict__ WT,
                                              const float* __restrict__ bias,
                                              void* __restrict__ out1,
                                              void* __restrict__ out2) {
  __shared__ __bf16 As[128][72];
  __shared__ __bf16 Ws[64][72];
  const int m0 = blockIdx.x * 128, n0 = blockIdx.y * 64;
  const int tid = threadIdx.x, lane = tid & 63, w = tid >> 6;
  const int wr = w >> 1, wcl = w & 1;
  const int l15 = lane & 15, l4 = lane >> 4;
  f32x4 acc[4][2] = {};
  for (int ks = 0; ks < KT; ks += 64) {
    const __bf16* Asrc; int lda, kb;
    if (ks < k1) { Asrc = A1; lda = lda1; kb = ks; }
    else         { Asrc = A2; lda = lda2; kb = ks - k1; }
#pragma unroll
    for (int it = 0; it < 4; ++it) {
      int idx = it * 256 + tid, r = idx >> 3, ch = idx & 7;
      *(bf16x8*)(&As[r][ch * 8]) = *(const bf16x8*)(Asrc + (size_t)(m0 + r) * lda + kb + ch * 8);
    }
#pragma unroll
    for (int it = 0; it < 2; ++it) {
      int idx = it * 256 + tid, r = idx >> 3, ch = idx & 7;
      *(bf16x8*)(&Ws[r][ch * 8]) = *(const bf16x8*)(WT + (size_t)(n0 + r) * KT + ks + ch * 8);
    }
    __syncthreads();
#pragma unroll
    for (int kk = 0; kk < 2; ++kk) {
      int krd = kk * 32 + l4 * 8;
      bf16x8 av[4], bv[2];
#pragma unroll
      for (int mi = 0; mi < 4; ++mi) av[mi] = *(const bf16x8*)(&As[wr * 64 + mi * 16 + l15][krd]);
#pragma unroll
      for (int ni = 0; ni < 2; ++ni) bv[ni] = *(const bf16x8*)(&Ws[wcl * 32 + ni * 16 + l15][krd]);
#pragma unroll
      for (int mi = 0; mi < 4; ++mi)
#pragma unroll
        for (int ni = 0; ni < 2; ++ni)
          acc[mi][ni] = __builtin_amdgcn_mfma_f32_16x16x32_bf16(av[mi], bv[ni], acc[mi][ni], 0, 0, 0);
    }
    __syncthreads();
  }
  if (MODE == 1) {
#pragma unroll
    for (int mi = 0; mi < 4; ++mi)
#pragma unroll
      for (int ni = 0; ni < 2; ++ni) {
        int col = n0 + wcl * 32 + ni * 16 + l15;
        float bcol = bias[col];
        int row0 = m0 + wr * 64 + mi * 16 + l4 * 4;
        float* out = (float*)out1;
#pragma unroll
        for (int r = 0; r < 4; ++r)
          out[(size_t)(row0 + r) * NC + col] = fmaxf(acc[mi][ni][r] + bcol, 0.f);
      }
  } else if (n0 < 128) {
    // fg path (cols < 128)
#pragma unroll
    for (int mi = 0; mi < 4; ++mi)
#pragma unroll
      for (int ni = 0; ni < 2; ++ni) {
        int col = n0 + wcl * 32 + ni * 16 + l15;
        float bcol = bias[col];
        int row0 = m0 + wr * 64 + mi * 16 + l4 * 4;
        __bf16* fg = (__bf16*)out1;
#pragma unroll
        for (int r = 0; r < 4; ++r)
          fg[(size_t)(row0 + r) * 128 + col] = (__bf16)(acc[mi][ni][r] + bcol);
      }
  } else {
    // hvT path: stage transpose in LDS (alias As: 64 x 136 = 17.4KB <= 18.4KB)
    __syncthreads();
    __bf16 (*Tt)[136] = (__bf16(*)[136])(&As[0][0]);
#pragma unroll
    for (int mi = 0; mi < 4; ++mi)
#pragma unroll
      for (int ni = 0; ni < 2; ++ni) {
        int dloc = wcl * 32 + ni * 16 + l15;
        float bcol = bias[n0 + dloc];
        int nloc = wr * 64 + mi * 16 + l4 * 4;
#pragma unroll
        for (int r = 0; r < 4; ++r)
          Tt[dloc][nloc + r] = (__bf16)(acc[mi][ni][r] + bcol);
      }
    __syncthreads();
    const int bb = m0 >> 12, n = m0 & 4095, d0 = n0 - 128;
    __bf16* hvT = (__bf16*)out2;
    const int rrow = tid >> 3, c8 = tid & 7;  // 32 rows x 8 chunk-threads
#pragma unroll
    for (int rep = 0; rep < 2; ++rep) {
      int dl = rrow + rep * 32;
      __bf16* dst = hvT + ((size_t)(bb * 256 + d0 + dl)) * 4096 + n;
      *(bf16x8*)(dst + c8 * 8) = *(const bf16x8*)(&Tt[dl][c8 * 8]);
      *(bf16x8*)(dst + 64 + c8 * 8) = *(const bf16x8*)(&Tt[dl][64 + c8 * 8]);
    }
  }
}

// ---------- attention ----------
// R2 proven config (QBLK=64, grid 256, 8 waves) + 2-deep V prefetch (ping-pong,
// statically unrolled x2) + conflict-free uint2 PsT writes.
__global__ __launch_bounds__(512, 2) void k_attn(const __bf16* __restrict__ fg,
                                                 const __bf16* __restrict__ hvT,
                                                 __bf16* __restrict__ obuf) {
  __shared__ __bf16 PsT[2][64][136];
  __shared__ float Lp[8][64];
  // XCD swizzle: batch b -> 2 XCDs (F+V slab L2-resident per XCD)
  const int id = blockIdx.x;
  const int xcd = id & 7, i2 = id >> 3;
  const int b = xcd >> 1;
  const int q0 = (i2 * 2 + (xcd & 1)) * 64;
  const int tid = threadIdx.x, w = tid >> 6, lane = tid & 63;
  const int l15 = lane & 15, l4 = lane >> 4;
  const __bf16* fgb = fg + (size_t)b * NPIX * 128;
  const __bf16* vb = hvT + (size_t)b * D2 * NPIX;

  // query fragments (resident)
  bf16x8 bG[4][2];
#pragma unroll
  for (int qt = 0; qt < 4; ++qt)
#pragma unroll
    for (int kk = 0; kk < 2; ++kk)
      bG[qt][kk] = *(const bf16x8*)(fgb + (size_t)(q0 + qt * 16 + l15) * 128 + 64 + kk * 32 + l4 * 8);

  // prologue: aF (tile 0), bVA (tile 0), bVB (tile 1)
  bf16x8 aF[2], bVA[2][4], bVB[2][4];
#pragma unroll
  for (int kk = 0; kk < 2; ++kk)
    aF[kk] = *(const bf16x8*)(fgb + (size_t)(w * 16 + l15) * 128 + kk * 32 + l4 * 8);
#pragma unroll
  for (int dj = 0; dj < 2; ++dj)
#pragma unroll
    for (int k4 = 0; k4 < 4; ++k4) {
      bVA[dj][k4] = *(const bf16x8*)(vb + (size_t)(w * 32 + dj * 16 + l15) * NPIX + k4 * 32 + l4 * 8);
      bVB[dj][k4] = *(const bf16x8*)(vb + (size_t)(w * 32 + dj * 16 + l15) * NPIX + 128 + k4 * 32 + l4 * 8);
    }

  f32x4 accO[4][2] = {};
  float lsum[4] = {0.f, 0.f, 0.f, 0.f};

  // body for tile T (0-indexed): uses BV (holds tile T), prefetches tile T+2 into BV
#define ABODY(T, BV) do {                                                               \
    const int mn1 = (((T) + 1) * 128) & (NPIX - 1);                                     \
    const int mn2 = (((T) + 2) * 128) & (NPIX - 1);                                     \
    const int bufi = (T) & 1;                                                           \
    f32x4 s[4];                                                                         \
    _Pragma("unroll")                                                                   \
    for (int qt = 0; qt < 4; ++qt) {                                                    \
      s[qt] = (f32x4){0.f, 0.f, 0.f, 0.f};                                              \
      _Pragma("unroll")                                                                 \
      for (int kk = 0; kk < 2; ++kk)                                                    \
        s[qt] = __builtin_amdgcn_mfma_f32_16x16x32_bf16(aF[kk], bG[qt][kk], s[qt], 0, 0, 0); \
    }                                                                                   \
    bf16x8 aFn[2];                                                                      \
    _Pragma("unroll")                                                                   \
    for (int kk = 0; kk < 2; ++kk)                                                      \
      aFn[kk] = *(const bf16x8*)(fgb + (size_t)(mn1 + w * 16 + l15) * 128 + kk * 32 + l4 * 8); \
    _Pragma("unroll")                                                                   \
    for (int qt = 0; qt < 4; ++qt) {                                                    \
      float p0 = __expf(s[qt][0]), p1 = __expf(s[qt][1]);                               \
      float p2 = __expf(s[qt][2]), p3 = __expf(s[qt][3]);                               \
      lsum[qt] += (p0 + p1) + (p2 + p3);                                                \
      union { __bf16 h[4]; uint2 u; } pk;                                               \
      pk.h[0] = (__bf16)p0; pk.h[1] = (__bf16)p1;                                       \
      pk.h[2] = (__bf16)p2; pk.h[3] = (__bf16)p3;                                       \
      *(uint2*)(&PsT[bufi][qt * 16 + l15][w * 16 + l4 * 4]) = pk.u;                     \
    }                                                                                   \
    RAW_BARRIER();                                                                      \
    _Pragma("unroll")                                                                   \
    for (int qt = 0; qt < 4; ++qt) {                                                    \
      bf16x8 aP[4];                                                                     \
      _Pragma("unroll")                                                                 \
      for (int k4 = 0; k4 < 4; ++k4)                                                    \
        aP[k4] = *(const bf16x8*)(&PsT[bufi][qt * 16 + l15][k4 * 32 + l4 * 8]);         \
      _Pragma("unroll")                                                                 \
      for (int dj = 0; dj < 2; ++dj)                                                    \
        _Pragma("unroll")                                                               \
        for (int k4 = 0; k4 < 4; ++k4)                                                  \
          accO[qt][dj] = __builtin_amdgcn_mfma_f32_16x16x32_bf16(aP[k4], BV[dj][k4], accO[qt][dj], 0, 0, 0); \
    }                                                                                   \
    _Pragma("unroll")                                                                   \
    for (int dj = 0; dj < 2; ++dj)                                                      \
      _Pragma("unroll")                                                                 \
      for (int k4 = 0; k4 < 4; ++k4)                                                    \
        BV[dj][k4] = *(const bf16x8*)(vb + (size_t)(w * 32 + dj * 16 + l15) * NPIX + mn2 + k4 * 32 + l4 * 8); \
    aF[0] = aFn[0]; aF[1] = aFn[1];                                                     \
  } while (0)

  for (int t = 0; t < 32; t += 2) {
    ABODY(t, bVA);
    ABODY(t + 1, bVB);
  }
#undef ABODY

  // ---- denominators: reduce lsum over l4 groups, then over waves via LDS ----
#pragma unroll
  for (int qt = 0; qt < 4; ++qt) {
    float v = lsum[qt];
    v += __shfl_xor(v, 16); v += __shfl_xor(v, 32);
    lsum[qt] = v;
  }
  if (l4 == 0) {
#pragma unroll
    for (int qt = 0; qt < 4; ++qt) Lp[w][qt * 16 + l15] = lsum[qt];
  }
  __syncthreads();
  float inv[4][4];
#pragma unroll
  for (int qt = 0; qt < 4; ++qt)
#pragma unroll
    for (int r = 0; r < 4; ++r) {
      int q = qt * 16 + l4 * 4 + r;
      float lt = 0.f;
#pragma unroll
      for (int ww = 0; ww < 8; ++ww) lt += Lp[ww][q];
      inv[qt][r] = 1.0f / lt;
    }
  __bf16* ob = obuf + ((size_t)b * NPIX + q0) * D2;
#pragma unroll
  for (int qt = 0; qt < 4; ++qt)
#pragma unroll
    for (int dj = 0; dj < 2; ++dj)
#pragma unroll
      for (int r = 0; r < 4; ++r)
        ob[(size_t)(qt * 16 + l4 * 4 + r) * D2 + w * 32 + dj * 16 + l15] =
            (__bf16)(accO[qt][dj][r] * inv[qt][r]);
}

// ---------- launch ----------
extern "C" void kernel_launch(void* const* d_in, const int* in_sizes, int n_in,
                              void* d_out, int out_size, void* d_ws, size_t ws_size,
                              hipStream_t stream) {
  const float* x = (const float*)d_in[0];
  const float* wf = (const float*)d_in[1];
  const float* bf_ = (const float*)d_in[2];
  const float* wg = (const float*)d_in[3];
  const float* bg_ = (const float*)d_in[4];
  const float* wh = (const float*)d_in[5];
  const float* bh_ = (const float*)d_in[6];
  const float* wo = (const float*)d_in[7];
  const float* bo = (const float*)d_in[8];
  const float* gamma = (const float*)d_in[9];
  const float* wc = (const float*)d_in[10];
  const float* bc = (const float*)d_in[11];
  const float* bns = (const float*)d_in[12];
  const float* bnb = (const float*)d_in[13];
  const float* bnm = (const float*)d_in[14];
  const float* bnv = (const float*)d_in[15];
  (void)in_sizes; (void)n_in; (void)out_size; (void)ws_size;

  char* ws = (char*)d_ws;
  __bf16* xb     = (__bf16*)(ws + 0);          // 16384*512*2  = 16,777,216
  __bf16* fg     = (__bf16*)(ws + 16777216);   // 16384*128*2  =  4,194,304
  __bf16* hvT    = (__bf16*)(ws + 20971520);   // 4*256*4096*2 =  8,388,608
  __bf16* obuf   = (__bf16*)(ws + 29360128);   // 16384*256*2  =  8,388,608
  __bf16* WfghT  = (__bf16*)(ws + 37748736);   // 384*512*2    =    393,216
  float*  bias384= (float*) (ws + 38141952);   // 384*4
  float*  Wow    = (float*) (ws + 38143488);   // 256*512*4    =    524,288
  __bf16* WcatT  = (__bf16*)(ws + 38667776);   // 512*768*2    =    786,432
  float*  biasF  = (float*) (ws + 39454208);   // 512*4  -> total ~39.5 MB
  float* out = (float*)d_out;

  hipLaunchKernelGGL(k_cvt, dim3(8192), dim3(256), 0, stream, x, xb, 2097152);
  hipLaunchKernelGGL(kp_wfgh, dim3(768), dim3(256), 0, stream, wf, wg, wh, WfghT);
  hipLaunchKernelGGL(kp_bias384, dim3(3), dim3(128), 0, stream, bf_, bg_, bh_, bias384);
  hipLaunchKernelGGL(kp_wow, dim3(512), dim3(256), 0, stream, wo, wc, Wow);
  hipLaunchKernelGGL(kp_wcat, dim3(1536), dim3(256), 0, stream, Wow, wc, gamma, bns, bnv, WcatT);
  hipLaunchKernelGGL(kp_biasF, dim3(2), dim3(256), 0, stream, bo, wc, bc, gamma, bns, bnb, bnm, bnv, biasF);
  hipLaunchKernelGGL((k_gemm<512, 384, 0>), dim3(128, 6), dim3(256), 0, stream,
                     xb, 512, 512, xb, 512, WfghT, bias384, (void*)fg, (void*)hvT);
  hipLaunchKernelGGL(k_attn, dim3(256), dim3(512), 0, stream, fg, hvT, obuf);
  hipLaunchKernelGGL((k_gemm<768, 512, 1>), dim3(128, 8), dim3(256), 0, stream,
                     obuf, 256, 256, xb, 512, WcatT, biasF, (void*)out, nullptr);
}